// Round 1
// baseline (519.942 us; speedup 1.0000x reference)
//
#include <hip/hip_runtime.h>
#include <math.h>

// Fused MLP 256->64->16->4 + global softmax over flattened [B*4].
// Layer1: lane = h1 column, 8 rows/wave, w1 transposed in LDS (2 K-halves),
// x via broadcast global_load_dwordx4. Layers 2/3 via per-wave LDS transpose
// + shuffle reduce. exp written unnormalized to d_out + atomic sum in d_ws;
// second kernel scales by 1/S.

#define WAVES_PER_BLOCK 4
#define ROWS_PER_WAVE 8
#define ROWS_PER_BLOCK (WAVES_PER_BLOCK * ROWS_PER_WAVE)   // 32
#define NBLOCKS (131072 / ROWS_PER_BLOCK)                  // 4096

__global__ __launch_bounds__(256, 3)
void mlp_kernel(const float* __restrict__ x, const float* __restrict__ w1,
                const float* __restrict__ b1, const float* __restrict__ w2,
                const float* __restrict__ b2, const float* __restrict__ w3,
                const float* __restrict__ b3, float* __restrict__ out,
                float* __restrict__ wsum)
{
    // 33792 + 4096 + 8704 = 46592 B  -> 3 blocks/CU
    __shared__ float w1th[64][132];          // w1 transposed, one K-half; pad 132 (stride%32==4)
    __shared__ float w2s[64][16];
    __shared__ float hs[WAVES_PER_BLOCK][8][68];  // per-wave h1 stash; pad 68

    const int tid  = threadIdx.x;
    const int lane = tid & 63;
    const int wid  = tid >> 6;

    // stage w2 once
    for (int i = tid; i < 64 * 16; i += 256) w2s[i >> 4][i & 15] = w2[i];

    const int rowbase = (blockIdx.x * WAVES_PER_BLOCK + wid) * ROWS_PER_WAVE;
    const float* xb = x + (size_t)rowbase * 256;

    float acc[ROWS_PER_WAVE];
#pragma unroll
    for (int i = 0; i < ROWS_PER_WAVE; ++i) acc[i] = 0.0f;

    for (int half = 0; half < 2; ++half) {
        const int k0 = half * 128;
        __syncthreads();   // all waves done with previous w1th contents
        // stage w1th[c][k] = w1[(k0+k)*64 + c], coalesced global read
        for (int i = tid; i < 64 * 128; i += 256) {
            const int c = i & 63;
            const int k = i >> 6;          // 0..127
            w1th[c][k] = w1[(size_t)(k0 + k) * 64 + c];
        }
        __syncthreads();

#pragma unroll 2
        for (int kc = 0; kc < 128; kc += 4) {
            const float4 wv = *(const float4*)&w1th[lane][kc];
            const float* xk = xb + k0 + kc;
#pragma unroll
            for (int i = 0; i < ROWS_PER_WAVE; ++i) {
                const float4 xv = *(const float4*)(xk + i * 256);  // broadcast load
                acc[i] = fmaf(xv.x, wv.x, acc[i]);
                acc[i] = fmaf(xv.y, wv.y, acc[i]);
                acc[i] = fmaf(xv.z, wv.z, acc[i]);
                acc[i] = fmaf(xv.w, wv.w, acc[i]);
            }
        }
    }

    // bias + relu -> per-wave LDS stash (transpose for layer 2)
    const float b1v = b1[lane];
#pragma unroll
    for (int i = 0; i < ROWS_PER_WAVE; ++i)
        hs[wid][i][lane] = fmaxf(acc[i] + b1v, 0.0f);
    __syncthreads();

    // layer 2: lane -> (row, t); lane computes z2[row][2t], z2[row][2t+1]
    const int row = lane >> 3;   // 0..7
    const int t   = lane & 7;    // 0..7
    const int j0  = t * 2;

    float z0 = b2[j0];
    float z1 = b2[j0 + 1];
#pragma unroll
    for (int c = 0; c < 64; c += 4) {
        const float4 h4 = *(const float4*)&hs[wid][row][c];
        const float2 wa = *(const float2*)&w2s[c + 0][j0];
        const float2 wb = *(const float2*)&w2s[c + 1][j0];
        const float2 wc = *(const float2*)&w2s[c + 2][j0];
        const float2 wd = *(const float2*)&w2s[c + 3][j0];
        z0 = fmaf(h4.x, wa.x, z0); z1 = fmaf(h4.x, wa.y, z1);
        z0 = fmaf(h4.y, wb.x, z0); z1 = fmaf(h4.y, wb.y, z1);
        z0 = fmaf(h4.z, wc.x, z0); z1 = fmaf(h4.z, wc.y, z1);
        z0 = fmaf(h4.w, wd.x, z0); z1 = fmaf(h4.w, wd.y, z1);
    }
    const float th0 = tanhf(z0);
    const float th1 = tanhf(z1);

    // layer 3 partials: p[c] over this lane's two j's
    const float4 w3a = *(const float4*)(w3 + (size_t)j0 * 4);
    const float4 w3b = *(const float4*)(w3 + (size_t)(j0 + 1) * 4);
    float p0 = th0 * w3a.x + th1 * w3b.x;
    float p1 = th0 * w3a.y + th1 * w3b.y;
    float p2 = th0 * w3a.z + th1 * w3b.z;
    float p3 = th0 * w3a.w + th1 * w3b.w;
#pragma unroll
    for (int off = 1; off <= 4; off <<= 1) {
        p0 += __shfl_xor(p0, off);
        p1 += __shfl_xor(p1, off);
        p2 += __shfl_xor(p2, off);
        p3 += __shfl_xor(p3, off);
    }

    float e = 0.0f;
    if (t < 4) {
        float lg = (t == 0) ? p0 : (t == 1) ? p1 : (t == 2) ? p2 : p3;
        lg += b3[t];
        e = expf(lg);   // |lg| <= ~20 -> no overflow in fp32
        out[(size_t)(rowbase + row) * 4 + t] = e;
    }

    // wave-sum of exp, one atomic per wave
    float s = e;
#pragma unroll
    for (int off = 1; off < 64; off <<= 1) s += __shfl_xor(s, off);
    if (lane == 0) atomicAdd(wsum, s);
}

__global__ __launch_bounds__(256)
void norm_kernel(float4* __restrict__ out, const float* __restrict__ wsum, int n4)
{
    const int i = blockIdx.x * 256 + threadIdx.x;
    if (i < n4) {
        const float inv = 1.0f / *wsum;
        float4 v = out[i];
        v.x *= inv; v.y *= inv; v.z *= inv; v.w *= inv;
        out[i] = v;
    }
}

extern "C" void kernel_launch(void* const* d_in, const int* in_sizes, int n_in,
                              void* d_out, int out_size, void* d_ws, size_t ws_size,
                              hipStream_t stream) {
    (void)in_sizes; (void)n_in; (void)ws_size;
    const float* x  = (const float*)d_in[0];
    const float* w1 = (const float*)d_in[1];
    const float* b1 = (const float*)d_in[2];
    const float* w2 = (const float*)d_in[3];
    const float* b2 = (const float*)d_in[4];
    const float* w3 = (const float*)d_in[5];
    const float* b3 = (const float*)d_in[6];
    float* out  = (float*)d_out;
    float* wsum = (float*)d_ws;

    hipMemsetAsync(wsum, 0, sizeof(float), stream);
    mlp_kernel<<<NBLOCKS, 256, 0, stream>>>(x, w1, b1, w2, b2, w3, b3, out, wsum);
    const int n4 = out_size >> 2;
    norm_kernel<<<(n4 + 255) / 256, 256, 0, stream>>>((float4*)out, wsum, n4);
}